// Round 1
// baseline (241.404 us; speedup 1.0000x reference)
//
#include <hip/hip_runtime.h>
#include <hip/hip_bf16.h>
#include <cmath>

// Problem constants
#define Bc   32
#define Sc_  512
#define Hc   768
#define NHc  12
#define DHc  64
#define Mc   (Bc * Sc_)     // 16384 tokens
#define Ntot (3 * Hc)       // 2304 fused output cols (Q|K|V)

// 0.125 (1/sqrt(DH)) * log2(e): folded into Q so softmax is exp2(s)
#define QSCALE 0.18033688011112042f

// Packed-panel stride: 12 K-tiles x 16384 ushorts (one 256-row/col panel)
#define PANEL 196608

typedef __attribute__((ext_vector_type(8))) short short8v;   // 8 bf16 (4 VGPRs)
typedef __attribute__((ext_vector_type(8))) unsigned short ushort8v;
typedef __attribute__((ext_vector_type(4))) float f32x4;     // MFMA acc

static __device__ __forceinline__ ushort f2b(float f) {
    __hip_bfloat16 h = __float2bfloat16(f);
    return *reinterpret_cast<ushort*>(&h);
}
static __device__ __forceinline__ ushort2 f2b2(float a, float b) {
    __hip_bfloat162 h = __float22bfloat162_rn(float2{a, b});
    return *reinterpret_cast<ushort2*>(&h);
}

// async global->LDS, 16B per lane. HW writes lane i to (wave-uniform lds)+i*16B.
static __device__ __forceinline__ void gl2lds(const ushort* g, ushort* l) {
    __builtin_amdgcn_global_load_lds(
        (const __attribute__((address_space(1))) unsigned int*)g,
        (__attribute__((address_space(3))) unsigned int*)l, 16, 0, 0);
}

// tanh(x) = 1 - 2/(exp2(2x*log2e)+1); exact at +/-inf via rcp(inf)=0
static __device__ __forceinline__ float fast_tanh(float x) {
    float e = __builtin_amdgcn_exp2f(x * 2.885390081777927f);
    return 1.0f - 2.0f * __builtin_amdgcn_rcpf(e + 1.0f);
}

// ---------------------------------------------------------------------------
// Kernel 0: fp32 -> bf16 tiled repack, coalesced both sides.
// NEW layout (for 256^2 8-phase GEMM, swizzle baked into the stream so that
// linear global_load_lds staging produces a bank-conflict-free LDS image):
//   Xt per 256-row M-panel pm: [kt(12)][half(2)][slot 8192 ushorts]
//     slot(r in 0..127, k in 0..63): idx = r*64 + ((k>>3 ^ (r&7))<<3) + (k&7)
//   Wt per 256-col N-panel pn: [kt(12)][kh(2)][slot 8192 ushorts]
//     slot(n in 0..255, k' in 0..31): idx = n*32 + (((k'>>3) ^ ((n>>1)&3))<<3) + (k'&7)
// ---------------------------------------------------------------------------
__global__ __launch_bounds__(256) void convert_pack(
    const float* __restrict__ X,
    const float* __restrict__ Wq, const float* __restrict__ Wk,
    const float* __restrict__ Wv,
    const float* __restrict__ bq, const float* __restrict__ bk,
    const float* __restrict__ bv,
    ushort* __restrict__ Xt, ushort* __restrict__ Wt, float* __restrict__ bbp)
{
    const int bx = blockIdx.x;
    const int panel = bx / 12, kcg = bx % 12;   // kcg = 64-k group (== kt)
    const int t = threadIdx.x;

    __shared__ ushort T[128][68];

    const float* base;
    ushort* out;
    const bool isX = panel < 128;
    int nhalf = 0;
    if (isX) {
        base = X + (size_t)panel * 128 * Hc;
        out  = Xt + (size_t)(panel >> 1) * PANEL + (size_t)(panel & 1) * 8192;
    } else {
        int nblk = panel - 128;                 // 0..17
        nhalf = nblk & 1;
        int n0 = nblk * 128;
        int z = n0 / Hc;
        int nn0 = n0 - z * Hc;
        const float* W = (z == 0) ? Wq : (z == 1) ? Wk : Wv;
        base = W + (size_t)nn0 * Hc;
        out  = Wt + (size_t)(nblk >> 1) * PANEL;
    }
    const int k0 = kcg * 64;

    const int slot = t & 15, rsub = t >> 4;
    #pragma unroll
    for (int rnd = 0; rnd < 8; ++rnd) {
        int row = rnd * 16 + rsub;
        const float* p = base + (size_t)row * Hc + k0 + slot * 4;
        float4 f = *(const float4*)p;
        ushort2 h0 = f2b2(f.x, f.y);
        ushort2 h1 = f2b2(f.z, f.w);
        ushort4 u;
        u.x = h0.x; u.y = h0.y; u.z = h1.x; u.w = h1.y;
        *(ushort4*)&T[row][slot * 4] = u;
    }
    __syncthreads();

    const int row_w = t & 127, khh = t >> 7;
    #pragma unroll
    for (int rnd = 0; rnd < 4; ++rnd) {
        int kc_l = rnd * 2 + khh;               // granule 0..7 within K-tile
        ushort4 lo = *(const ushort4*)&T[row_w][kc_l * 8];
        ushort4 hi = *(const ushort4*)&T[row_w][kc_l * 8 + 4];
        ushort8v o;
        o[0] = lo.x; o[1] = lo.y; o[2] = lo.z; o[3] = lo.w;
        o[4] = hi.x; o[5] = hi.y; o[6] = hi.z; o[7] = hi.w;
        size_t oidx;
        if (isX) {
            oidx = (size_t)kcg * 16384 + (size_t)row_w * 64
                 + (size_t)((kc_l ^ (row_w & 7)) << 3);
        } else {
            int n = nhalf * 128 + row_w;        // 0..255 within N-panel
            oidx = (size_t)kcg * 16384 + (size_t)(kc_l >> 2) * 8192
                 + (size_t)n * 32 + (size_t)((((kc_l & 3) ^ ((n >> 1) & 3)) << 3));
        }
        *(ushort8v*)&out[oidx] = o;
    }

    if (bx == 0) {
        for (int i = t; i < Ntot; i += 256) {
            int z2 = i / Hc, nn = i - z2 * Hc;
            bbp[i] = ((z2 == 0) ? bq : (z2 == 1) ? bk : bv)[nn];
        }
    }
}

// ---------------------------------------------------------------------------
// Kernel 1: fused QKV projection — 256x256 tile, BK=64, 8 waves, 8-phase
// schedule with counted vmcnt (T3+T4), LDS XOR-swizzle (T2), setprio (T5).
// Double-buffered 128 KiB LDS; per-phase: ds_reads -> stage 1 half-slot
// of kt+1 -> barrier -> 16 MFMA -> [counted vmcnt] -> barrier.
// Stage slots: A0/A1 = M-halves (128x64), Bk0/Bk1 = K-halves (256x32).
// vmcnt(4) end of phase1 lands Bk1(kt) before phase2 reads it;
// vmcnt(2) at K-tile boundary lands A0/A1/Bk0(kt+1), leaves Bk1 in flight.
// Epilogue layouts (per head, head stride S*DH = 32768) unchanged:
//   Qb: [s][d] row-major, pre-scaled by QSCALE
//   Kt: [kb=s/64][dchunk=d/8][s%64][8]
//   Vt: [kb=s/64][keychunk=(s%64)/8][d][8]
// ---------------------------------------------------------------------------
static __device__ __forceinline__ void stage_slot(const ushort* g, ushort* l,
                                                  int wv, int lane) {
    const int c0 = wv * 1024;                   // wave's two 512-ushort chunks
    gl2lds(g + c0 + lane * 8,       l + c0);
    gl2lds(g + c0 + 512 + lane * 8, l + c0 + 512);
}

#define BAR    __builtin_amdgcn_s_barrier()
#define VMW(n) asm volatile("s_waitcnt vmcnt(" #n ")" ::: "memory")

#define PH_A_READS(kh) \
    _Pragma("unroll") \
    for (int mf = 0; mf < 8; ++mf) \
        a[mf] = *(const short8v*)&As[ab + mf * 1024 + ((((kh) * 4 + quad) ^ rs) << 3)];

#define PH_B_READS(kh, nq) \
    b0 = *(const short8v*)&Bs[bb + (kh) * 8192 + ((nq) * 2) * 512 + bswz]; \
    b1 = *(const short8v*)&Bs[bb + (kh) * 8192 + ((nq) * 2 + 1) * 512 + bswz];

#define PH_MFMA(nq) \
    __builtin_amdgcn_s_setprio(1); \
    _Pragma("unroll") \
    for (int mf = 0; mf < 8; ++mf) { \
        acc[mf][(nq) * 2]     = __builtin_amdgcn_mfma_f32_16x16x32_bf16( \
            a[mf], b0, acc[mf][(nq) * 2], 0, 0, 0); \
        acc[mf][(nq) * 2 + 1] = __builtin_amdgcn_mfma_f32_16x16x32_bf16( \
            a[mf], b1, acc[mf][(nq) * 2 + 1], 0, 0, 0); \
    } \
    __builtin_amdgcn_s_setprio(0);

__global__ __launch_bounds__(512, 2) void qkv_mfma(
    const ushort* __restrict__ Xt, const ushort* __restrict__ Wt,
    const float* __restrict__ bbp,
    ushort* __restrict__ Qb, ushort* __restrict__ Kt, ushort* __restrict__ Vt)
{
    __shared__ __align__(16) ushort As[32768];   // [buf][half 128x64] 64 KiB
    __shared__ __align__(16) ushort Bs[32768];   // [buf][kh 256x32]   64 KiB

    const int tid = threadIdx.x;
    const int wv = tid >> 6, lane = tid & 63;
    const int quad = lane >> 4, l16 = lane & 15;
    const int wr = wv >> 2, wc = wv & 3;         // 2(M) x 4(N) waves

    // XCD-aware swizzle: 576 blocks = 8 XCDs x 72; each XCD gets 8 M-panels
    // across all 9 N-panels (Xt working set 3 MB + Wt 3.4 MB -> L2-resident).
    const int bid = blockIdx.x;
    const int swz = (bid & 7) * 72 + (bid >> 3);
    const int bx = swz / 9, by = swz % 9;        // M-panel, N-panel

    const ushort* gA = Xt + (size_t)bx * PANEL;
    const ushort* gB = Wt + (size_t)by * PANEL;

    f32x4 acc[8][4];
    #pragma unroll
    for (int i = 0; i < 8; ++i)
        #pragma unroll
        for (int j = 0; j < 4; ++j) acc[i][j] = (f32x4)(0.f);

    const int rs   = l16 & 7;                        // A swizzle key
    const int bswz = (quad ^ ((l16 >> 1) & 3)) << 3; // B swizzle (2-way max)
    const int arow = l16 * 64;
    const int brow = (wc * 64 + l16) * 32;

    short8v a[8], b0, b1;

    // Prologue: stage K-tile 0 into buf0; land all but the newest half-slot.
    stage_slot(gA,        As,        wv, lane);   // A0
    stage_slot(gA + 8192, As + 8192, wv, lane);   // A1
    stage_slot(gB,        Bs,        wv, lane);   // Bk0
    stage_slot(gB + 8192, Bs + 8192, wv, lane);   // Bk1 (may stay in flight)
    VMW(2);
    BAR;

    for (int kt = 0; kt < 11; ++kt) {
        const int cur = kt & 1;
        const ushort* gAn = gA + (size_t)(kt + 1) * 16384;
        const ushort* gBn = gB + (size_t)(kt + 1) * 16384;
        ushort* lAn = As + (cur ^ 1) * 16384;
        ushort* lBn = Bs + (cur ^ 1) * 16384;
        const int ab = cur * 16384 + wr * 8192 + arow;
        const int bb = cur * 16384 + brow;

        // phase 0: (nq0, kh0); stage A0(kt+1)
        PH_A_READS(0)
        PH_B_READS(0, 0)
        stage_slot(gAn, lAn, wv, lane);
        BAR;
        PH_MFMA(0)
        BAR;

        // phase 1: (nq1, kh0); stage A1(kt+1); vmcnt(4) lands Bk1(kt)
        PH_B_READS(0, 1)
        stage_slot(gAn + 8192, lAn + 8192, wv, lane);
        BAR;
        PH_MFMA(1)
        VMW(4);
        BAR;

        // phase 2: (nq0, kh1); stage Bk0(kt+1)
        PH_A_READS(1)
        PH_B_READS(1, 0)
        stage_slot(gBn, lBn, wv, lane);
        BAR;
        PH_MFMA(0)
        BAR;

        // phase 3: (nq1, kh1); stage Bk1(kt+1); boundary vmcnt(2)
        PH_B_READS(1, 1)
        stage_slot(gBn + 8192, lBn + 8192, wv, lane);
        BAR;
        PH_MFMA(1)
        VMW(2);
        BAR;
    }

    // Tail K-tile kt=11 (buf1), no stages; drain Bk1(11) before phase 2.
    {
        const int ab = 16384 + wr * 8192 + arow;
        const int bb = 16384 + brow;

        PH_A_READS(0)
        PH_B_READS(0, 0)
        BAR;
        PH_MFMA(0)
        BAR;

        PH_B_READS(0, 1)
        BAR;
        PH_MFMA(1)
        VMW(0);
        BAR;

        PH_A_READS(1)
        PH_B_READS(1, 0)
        BAR;
        PH_MFMA(0)
        BAR;

        PH_B_READS(1, 1)
        BAR;
        PH_MFMA(1)
    }

    // Epilogue. C 16x16 tile: col=l16 (n-dir), row=quad*4+r (m-dir).
    const int z = by / 3;                        // 0=Q, 1=K, 2=V (block-uniform)
    #pragma unroll
    for (int nf = 0; nf < 4; ++nf) {
        const int n  = by * 256 + wc * 64 + nf * 16 + l16;
        const int nn = n - z * Hc;
        const int h  = nn >> 6, d = nn & 63;
        const float bias = bbp[n];
        #pragma unroll
        for (int mf = 0; mf < 8; ++mf) {
            const int mbase = bx * 256 + wr * 128 + mf * 16 + quad * 4;
            const int bb2 = mbase >> 9;
            const int s0 = mbase & 511;
            const size_t head = (size_t)(bb2 * NHc + h) * (Sc_ * DHc);
            if (z == 0) {
                size_t basep = head + (size_t)s0 * DHc + d;
                #pragma unroll
                for (int r = 0; r < 4; ++r)
                    Qb[basep + (size_t)r * DHc] = f2b((acc[mf][nf][r] + bias) * QSCALE);
            } else if (z == 1) {
                size_t basep = head + (s0 >> 6) * 4096 + (d >> 3) * 512
                             + (s0 & 63) * 8 + (d & 7);
                #pragma unroll
                for (int r = 0; r < 4; ++r)
                    Kt[basep + r * 8] = f2b(acc[mf][nf][r] + bias);
            } else {
                size_t basep = head + (s0 >> 6) * 4096 + ((s0 & 63) >> 3) * 512
                             + d * 8 + (s0 & 7);
                ushort4 o;
                o.x = f2b(acc[mf][nf][0] + bias);
                o.y = f2b(acc[mf][nf][1] + bias);
                o.z = f2b(acc[mf][nf][2] + bias);
                o.w = f2b(acc[mf][nf][3] + bias);
                *(ushort4*)&Vt[basep] = o;
            }
        }
    }
}

// ---------------------------------------------------------------------------
// Kernel 2 (unchanged): attention, 256 q per block (wave = 64 q = 4 u-tiles).
// ---------------------------------------------------------------------------
__global__ __launch_bounds__(256, 2) void attn_mfma(
    const ushort* __restrict__ Qb, const ushort* __restrict__ Kt,
    const ushort* __restrict__ Vt, float* __restrict__ out)
{
    const int bid = blockIdx.x;
    const int super = bid >> 4, l = bid & 15;
    const int head_lin = super * 8 + (l & 7);     // 0..383
    const int qhalf = l >> 3;                     // 0..1
    const int b = head_lin / NHc, h = head_lin % NHc;

    const int wave = threadIdx.x >> 6;
    const int lane = threadIdx.x & 63;
    const int quad = lane >> 4, l16 = lane & 15;
    const int q0 = qhalf * 256 + wave * 64;       // wave owns q0..q0+63
    const int sw = l16 & 7;                       // XOR swizzle key

    const size_t head = (size_t)head_lin * (Sc_ * DHc);
    const ushort* __restrict__ Q = Qb + head;
    const ushort* __restrict__ K = Kt + head;
    const ushort* __restrict__ V = Vt + head;

    __shared__ __align__(16) ushort Plds[4][1024];   // wave-private, reused per utile

    short8v aq[4][2];
    #pragma unroll
    for (int u = 0; u < 4; ++u)
        #pragma unroll
        for (int hf = 0; hf < 2; ++hf)
            aq[u][hf] = *(const short8v*)
                &Q[(size_t)(q0 + u * 16 + l16) * DHc + hf * 32 + quad * 8];

    short8v ones;
    #pragma unroll
    for (int i = 0; i < 8; ++i) ones[i] = (short)0x3F80;   // bf16 1.0

    f32x4 o[4][4], rsum[4];
    #pragma unroll
    for (int u = 0; u < 4; ++u) {
        rsum[u] = (f32x4)(0.f);
        #pragma unroll
        for (int t = 0; t < 4; ++t) o[u][t] = (f32x4)(0.f);
    }

    for (int kb = 0; kb < 8; ++kb) {
        const ushort* Kb_ = K + kb * 4096;
        const ushort* Vb_ = V + kb * 4096;

        // K/V fragments, shared by all 4 u-tiles of this wave
        short8v kf[4][2], vf[4][2];
        #pragma unroll
        for (int t = 0; t < 4; ++t) {
            kf[t][0] = *(const short8v*)&Kb_[quad * 512 + (t * 16 + l16) * 8];
            kf[t][1] = *(const short8v*)&Kb_[(4 + quad) * 512 + (t * 16 + l16) * 8];
            vf[t][0] = *(const short8v*)&Vb_[quad * 512 + (t * 16 + l16) * 8];
            vf[t][1] = *(const short8v*)&Vb_[(4 + quad) * 512 + (t * 16 + l16) * 8];
        }

        #pragma unroll
        for (int u = 0; u < 4; ++u) {
            // S^T: D[key=quad*4+r][q=l16]
            f32x4 sa[4];
            #pragma unroll
            for (int t = 0; t < 4; ++t) {
                f32x4 s = __builtin_amdgcn_mfma_f32_16x16x32_bf16(
                    kf[t][0], aq[u][0], (f32x4)(0.f), 0, 0, 0);
                sa[t] = __builtin_amdgcn_mfma_f32_16x16x32_bf16(
                    kf[t][1], aq[u][1], s, 0, 0, 0);
            }

            // p = exp2(s~), pack to bf16, stage to LDS (wave-private)
            #pragma unroll
            for (int t = 0; t < 4; ++t) {
                float p0 = __builtin_amdgcn_exp2f(sa[t][0]);
                float p1 = __builtin_amdgcn_exp2f(sa[t][1]);
                float p2 = __builtin_amdgcn_exp2f(sa[t][2]);
                float p3 = __builtin_amdgcn_exp2f(sa[t][3]);
                ushort2 lo = f2b2(p0, p1);
                ushort2 hi = f2b2(p2, p3);
                ushort4 pk;
                pk.x = lo.x; pk.y = lo.y; pk.z = hi.x; pk.w = hi.y;
                int c = t * 2 + (quad >> 1);            // key chunk 0..7
                int addr = l16 * 64 + ((c ^ sw) * 8) + (quad & 1) * 4;
                *(ushort4*)&Plds[wave][addr] = pk;
            }

            // P A-frags (q = l16, key chunk = hf*4+quad, swizzled)
            short8v pa0 = *(const short8v*)&Plds[wave][l16 * 64 + ((quad ^ sw) * 8)];
            short8v pa1 = *(const short8v*)&Plds[wave][l16 * 64 + (((4 + quad) ^ sw) * 8)];

            // row sums via ones-MFMA
            rsum[u] = __builtin_amdgcn_mfma_f32_16x16x32_bf16(
                pa0, ones, rsum[u], 0, 0, 0);
            rsum[u] = __builtin_amdgcn_mfma_f32_16x16x32_bf16(
                pa1, ones, rsum[u], 0, 0, 0);

            // PV: O[q=quad*4+r][d=l16]
            #pragma unroll
            for (int t2 = 0; t2 < 4; ++t2) {
                o[u][t2] = __builtin_amdgcn_mfma_f32_16x16x32_bf16(
                    pa0, vf[t2][0], o[u][t2], 0, 0, 0);
                o[u][t2] = __builtin_amdgcn_mfma_f32_16x16x32_bf16(
                    pa1, vf[t2][1], o[u][t2], 0, 0, 0);
            }
        }
    }

    // Epilogue: normalize, tanh, store.
    #pragma unroll
    for (int u = 0; u < 4; ++u) {
        #pragma unroll
        for (int r = 0; r < 4; ++r) {
            float inv = __builtin_amdgcn_rcpf(rsum[u][r]);
            int q = q0 + u * 16 + quad * 4 + r;
            size_t base = ((size_t)b * Sc_ + q) * Hc + h * DHc;
            #pragma unroll
            for (int t2 = 0; t2 < 4; ++t2)
                out[base + t2 * 16 + l16] = fast_tanh(o[u][t2][r] * inv);
        }
    }
}

extern "C" void kernel_launch(void* const* d_in, const int* in_sizes, int n_in,
                              void* d_out, int out_size, void* d_ws, size_t ws_size,
                              hipStream_t stream) {
    const float* X  = (const float*)d_in[0];
    const float* Wq = (const float*)d_in[1];
    const float* bq = (const float*)d_in[2];
    const float* Wk = (const float*)d_in[3];
    const float* bk = (const float*)d_in[4];
    const float* Wv = (const float*)d_in[5];
    const float* bv = (const float*)d_in[6];
    float* out = (float*)d_out;

    ushort* Qb  = (ushort*)d_ws;
    ushort* Kt  = Qb + (size_t)Mc * Hc;
    ushort* Vt  = Kt + (size_t)Mc * Hc;
    ushort* Xt  = Vt + (size_t)Mc * Hc;
    ushort* Wt  = Xt + (size_t)Mc * Hc;
    float*  bbp = (float*)(Wt + (size_t)Ntot * Hc);

    convert_pack<<<dim3(1752), 256, 0, stream>>>(
        X, Wq, Wk, Wv, bq, bk, bv, Xt, Wt, bbp);

    qkv_mfma<<<dim3(576), 512, 0, stream>>>(Xt, Wt, bbp, Qb, Kt, Vt);

    attn_mfma<<<dim3(768), 256, 0, stream>>>(Qb, Kt, Vt, out);
}

// Round 2
// 226.067 us; speedup vs baseline: 1.0678x; 1.0678x over previous
//
#include <hip/hip_runtime.h>
#include <hip/hip_bf16.h>
#include <cmath>

// Problem constants
#define Bc   32
#define Sc_  512
#define Hc   768
#define NHc  12
#define DHc  64
#define Mc   (Bc * Sc_)     // 16384 tokens
#define Ntot (3 * Hc)       // 2304 fused output cols (Q|K|V)

// 0.125 (1/sqrt(DH)) * log2(e): folded into Q so softmax is exp2(s)
#define QSCALE 0.18033688011112042f

// Packed-panel stride: 12 K-tiles x 16384 ushorts (one 256-row/col panel)
#define PANEL 196608

typedef __attribute__((ext_vector_type(8))) short short8v;   // 8 bf16 (4 VGPRs)
typedef __attribute__((ext_vector_type(8))) unsigned short ushort8v;
typedef __attribute__((ext_vector_type(4))) float f32x4;     // MFMA acc

static __device__ __forceinline__ ushort f2b(float f) {
    __hip_bfloat16 h = __float2bfloat16(f);
    return *reinterpret_cast<ushort*>(&h);
}
static __device__ __forceinline__ ushort2 f2b2(float a, float b) {
    __hip_bfloat162 h = __float22bfloat162_rn(float2{a, b});
    return *reinterpret_cast<ushort2*>(&h);
}

// async global->LDS, 16B per lane. HW writes lane i to (wave-uniform lds)+i*16B.
static __device__ __forceinline__ void gl2lds(const ushort* g, ushort* l) {
    __builtin_amdgcn_global_load_lds(
        (const __attribute__((address_space(1))) unsigned int*)g,
        (__attribute__((address_space(3))) unsigned int*)l, 16, 0, 0);
}

// tanh(x) = 1 - 2/(exp2(2x*log2e)+1); exact at +/-inf via rcp(inf)=0
static __device__ __forceinline__ float fast_tanh(float x) {
    float e = __builtin_amdgcn_exp2f(x * 2.885390081777927f);
    return 1.0f - 2.0f * __builtin_amdgcn_rcpf(e + 1.0f);
}

// ---------------------------------------------------------------------------
// Kernel 0: fp32 -> bf16 tiled repack.
// Layout (per 256-row/col panel, per K-tile kt, per k-half kh):
//   slot[kh] = 8192 ushorts: idx = row*32 + ((g ^ ((row>>1)&3))<<3) + (k'&7)
//   where row in [0,256), k' = k - kh*32 in [0,32), g = k'>>3.
// Slots are staged linearly by global_load_lds, so global order == LDS order;
// the XOR makes the GEMM's ds_read_b128 2-way max (free).
// Global writes are arranged as contiguous 16B x 64-lane stores.
// ---------------------------------------------------------------------------
__global__ __launch_bounds__(256) void convert_pack(
    const float* __restrict__ X,
    const float* __restrict__ Wq, const float* __restrict__ Wk,
    const float* __restrict__ Wv,
    const float* __restrict__ bq, const float* __restrict__ bk,
    const float* __restrict__ bv,
    ushort* __restrict__ Xt, ushort* __restrict__ Wt, float* __restrict__ bbp)
{
    const int bx = blockIdx.x;
    const int panel = bx / 12, kcg = bx % 12;   // kcg = K-tile index
    const int t = threadIdx.x;

    __shared__ ushort T[128][68];

    const float* base;
    ushort* out;
    int half128;
    if (panel < 128) {
        base = X + (size_t)panel * 128 * Hc;
        out  = Xt + (size_t)(panel >> 1) * PANEL;
        half128 = panel & 1;
    } else {
        int nblk = panel - 128;                 // 0..17
        half128 = nblk & 1;
        int n0 = nblk * 128;
        int z = n0 / Hc;
        int nn0 = n0 - z * Hc;
        const float* W = (z == 0) ? Wq : (z == 1) ? Wk : Wv;
        base = W + (size_t)nn0 * Hc;
        out  = Wt + (size_t)(nblk >> 1) * PANEL;
    }
    const int k0 = kcg * 64;

    const int slot = t & 15, rsub = t >> 4;
    #pragma unroll
    for (int rnd = 0; rnd < 8; ++rnd) {
        int row = rnd * 16 + rsub;
        const float* p = base + (size_t)row * Hc + k0 + slot * 4;
        float4 f = *(const float4*)p;
        ushort2 h0 = f2b2(f.x, f.y);
        ushort2 h1 = f2b2(f.z, f.w);
        ushort4 u;
        u.x = h0.x; u.y = h0.y; u.z = h1.x; u.w = h1.y;
        *(ushort4*)&T[row][slot * 4] = u;
    }
    __syncthreads();

    // Writeback: lane = (rowl, gslot); contiguous 16B stores per 64-lane wave.
    const int gslot = t & 3, rowl = t >> 2;      // rowl 0..63
    #pragma unroll
    for (int rnd = 0; rnd < 4; ++rnd) {
        const int kh = rnd >> 1;
        const int row_w = (rnd & 1) * 64 + rowl; // 0..127 within this block
        const int rowg = half128 * 128 + row_w;  // 0..255 within panel
        const int g = gslot ^ ((rowg >> 1) & 3); // source granule for this slot
        const int kc_l = kh * 4 + g;             // granule within K-tile
        ushort4 lo = *(const ushort4*)&T[row_w][kc_l * 8];
        ushort4 hi = *(const ushort4*)&T[row_w][kc_l * 8 + 4];
        ushort8v o;
        o[0] = lo.x; o[1] = lo.y; o[2] = lo.z; o[3] = lo.w;
        o[4] = hi.x; o[5] = hi.y; o[6] = hi.z; o[7] = hi.w;
        *(ushort8v*)&out[(size_t)kcg * 16384 + (size_t)kh * 8192
                         + (size_t)rowg * 32 + gslot * 8] = o;
    }

    if (bx == 0) {
        for (int i = t; i < Ntot; i += 256) {
            int z2 = i / Hc, nn = i - z2 * Hc;
            bbp[i] = ((z2 == 0) ? bq : (z2 == 1) ? bk : bv)[nn];
        }
    }
}

// ---------------------------------------------------------------------------
// Kernel 1: fused QKV projection — 256x256 tile, BK=64, 8 waves, 4-phase/K-tile
// schedule with counted vmcnt, K-half-granular stage slots (staggered
// deadlines: kh0 slots needed ph0, kh1 slots needed ph2), LDS XOR-swizzle,
// setprio. Waits are vmcnt(4) twice per K-tile; every waited load was issued
// >=2 full MFMA phases earlier. Never drains below 4 outstanding.
// Epilogue layouts (per head, head stride S*DH = 32768) unchanged:
//   Qb: [s][d] row-major, pre-scaled by QSCALE
//   Kt: [kb=s/64][dchunk=d/8][s%64][8]
//   Vt: [kb=s/64][keychunk=(s%64)/8][d][8]
// ---------------------------------------------------------------------------
static __device__ __forceinline__ void stage_slot(const ushort* g, ushort* l,
                                                  int wv, int lane) {
    const int c0 = wv * 1024;                   // wave's two 512-ushort chunks
    gl2lds(g + c0 + lane * 8,       l + c0);
    gl2lds(g + c0 + 512 + lane * 8, l + c0 + 512);
}

#define BAR    __builtin_amdgcn_s_barrier()
#define VMW(n) asm volatile("s_waitcnt vmcnt(" #n ")" ::: "memory")

#define PH_A_READS(kh) \
    _Pragma("unroll") \
    for (int mf = 0; mf < 8; ++mf) \
        a[mf] = *(const short8v*)&As[cbase + (kh) * 8192 + mf * 512 + aoff];

#define PH_B_READS(kh, nq) \
    b0 = *(const short8v*)&Bs[cbase + (kh) * 8192 + (nq) * 1024 + boff]; \
    b1 = *(const short8v*)&Bs[cbase + (kh) * 8192 + (nq) * 1024 + 512 + boff];

#define PH_MFMA(nq) \
    __builtin_amdgcn_s_setprio(1); \
    _Pragma("unroll") \
    for (int mf = 0; mf < 8; ++mf) { \
        acc[mf][(nq) * 2]     = __builtin_amdgcn_mfma_f32_16x16x32_bf16( \
            a[mf], b0, acc[mf][(nq) * 2], 0, 0, 0); \
        acc[mf][(nq) * 2 + 1] = __builtin_amdgcn_mfma_f32_16x16x32_bf16( \
            a[mf], b1, acc[mf][(nq) * 2 + 1], 0, 0, 0); \
    } \
    __builtin_amdgcn_s_setprio(0);

__global__ __launch_bounds__(512, 2) void qkv_mfma(
    const ushort* __restrict__ Xt, const ushort* __restrict__ Wt,
    const float* __restrict__ bbp,
    ushort* __restrict__ Qb, ushort* __restrict__ Kt, ushort* __restrict__ Vt)
{
    __shared__ __align__(16) ushort As[32768];   // [buf][kh: 256 rows x 32 k]
    __shared__ __align__(16) ushort Bs[32768];   // [buf][kh: 256 cols x 32 k]

    const int tid = threadIdx.x;
    const int wv = tid >> 6, lane = tid & 63;
    const int quad = lane >> 4, l16 = lane & 15;
    const int wr = wv >> 2, wc = wv & 3;         // 2(M) x 4(N) waves

    // XCD-aware swizzle: 576 blocks = 8 XCDs x 72; each XCD: 8 bx x 9 by
    // (A 3 MB + B 3.4 MB working set ~ L2-resident per XCD).
    const int bid = blockIdx.x;
    const int swz = (bid & 7) * 72 + (bid >> 3);
    const int bx = swz / 9, by = swz % 9;        // M-panel, N-panel

    const ushort* gA = Xt + (size_t)bx * PANEL;
    const ushort* gB = Wt + (size_t)by * PANEL;

    f32x4 acc[8][4];
    #pragma unroll
    for (int i = 0; i < 8; ++i)
        #pragma unroll
        for (int j = 0; j < 4; ++j) acc[i][j] = (f32x4)(0.f);

    const int aswz = ((quad ^ ((l16 >> 1) & 3)) << 3);
    const int aoff = (wr * 128 + l16) * 32 + aswz;
    const int boff = (wc * 64 + l16) * 32 + aswz;

    short8v a[8], b0, b1;

    // Prologue: stage K-tile 0 (kh0 slots first), land kh0, keep kh1 in flight.
    stage_slot(gA,        As,        wv, lane);   // A-kh0(0)
    stage_slot(gB,        Bs,        wv, lane);   // B-kh0(0)
    stage_slot(gA + 8192, As + 8192, wv, lane);   // A-kh1(0)
    stage_slot(gB + 8192, Bs + 8192, wv, lane);   // B-kh1(0)
    VMW(4);
    BAR;

    for (int kt = 0; kt < 11; ++kt) {
        const int cur = kt & 1;
        const ushort* gAn = gA + (size_t)(kt + 1) * 16384;
        const ushort* gBn = gB + (size_t)(kt + 1) * 16384;
        ushort* lAn = As + (cur ^ 1) * 16384;
        ushort* lBn = Bs + (cur ^ 1) * 16384;
        const int cbase = cur * 16384;

        // ph0 (kh0, nq0); stage A-kh0(kt+1)
        PH_A_READS(0)
        PH_B_READS(0, 0)
        stage_slot(gAn, lAn, wv, lane);
        BAR;
        PH_MFMA(0)
        BAR;

        // ph1 (kh0, nq1); stage B-kh0(kt+1); vmcnt(4) lands kh1(kt)
        PH_B_READS(0, 1)
        stage_slot(gBn, lBn, wv, lane);
        BAR;
        PH_MFMA(1)
        VMW(4);
        BAR;

        // ph2 (kh1, nq0); stage A-kh1(kt+1)
        PH_A_READS(1)
        PH_B_READS(1, 0)
        stage_slot(gAn + 8192, lAn + 8192, wv, lane);
        BAR;
        PH_MFMA(0)
        BAR;

        // ph3 (kh1, nq1); stage B-kh1(kt+1); vmcnt(4) lands kh0(kt+1)
        PH_B_READS(1, 1)
        stage_slot(gBn + 8192, lBn + 8192, wv, lane);
        BAR;
        PH_MFMA(1)
        VMW(4);
        BAR;
    }

    // Tail K-tile kt=11 (buf1), no staging; drain kh1(11) before ph2 reads.
    {
        const int cbase = 16384;

        PH_A_READS(0)
        PH_B_READS(0, 0)
        BAR;
        PH_MFMA(0)
        BAR;

        PH_B_READS(0, 1)
        BAR;
        PH_MFMA(1)
        VMW(0);
        BAR;

        PH_A_READS(1)
        PH_B_READS(1, 0)
        BAR;
        PH_MFMA(0)
        BAR;

        PH_B_READS(1, 1)
        BAR;
        PH_MFMA(1)
    }

    // Epilogue. C 16x16 tile: col=l16 (n-dir), row=quad*4+r (m-dir).
    const int z = by / 3;                        // 0=Q, 1=K, 2=V (block-uniform)
    #pragma unroll
    for (int nf = 0; nf < 4; ++nf) {
        const int n  = by * 256 + wc * 64 + nf * 16 + l16;
        const int nn = n - z * Hc;
        const int h  = nn >> 6, d = nn & 63;
        const float bias = bbp[n];
        #pragma unroll
        for (int mf = 0; mf < 8; ++mf) {
            const int mbase = bx * 256 + wr * 128 + mf * 16 + quad * 4;
            const int bb2 = mbase >> 9;
            const int s0 = mbase & 511;
            const size_t head = (size_t)(bb2 * NHc + h) * (Sc_ * DHc);
            if (z == 0) {
                size_t basep = head + (size_t)s0 * DHc + d;
                #pragma unroll
                for (int r = 0; r < 4; ++r)
                    Qb[basep + (size_t)r * DHc] = f2b((acc[mf][nf][r] + bias) * QSCALE);
            } else if (z == 1) {
                size_t basep = head + (s0 >> 6) * 4096 + (d >> 3) * 512
                             + (s0 & 63) * 8 + (d & 7);
                #pragma unroll
                for (int r = 0; r < 4; ++r)
                    Kt[basep + r * 8] = f2b(acc[mf][nf][r] + bias);
            } else {
                size_t basep = head + (s0 >> 6) * 4096 + ((s0 & 63) >> 3) * 512
                             + d * 8 + (s0 & 7);
                ushort4 o;
                o.x = f2b(acc[mf][nf][0] + bias);
                o.y = f2b(acc[mf][nf][1] + bias);
                o.z = f2b(acc[mf][nf][2] + bias);
                o.w = f2b(acc[mf][nf][3] + bias);
                *(ushort4*)&Vt[basep] = o;
            }
        }
    }
}

// ---------------------------------------------------------------------------
// Kernel 2 (unchanged): attention, 256 q per block (wave = 64 q = 4 u-tiles).
// ---------------------------------------------------------------------------
__global__ __launch_bounds__(256, 2) void attn_mfma(
    const ushort* __restrict__ Qb, const ushort* __restrict__ Kt,
    const ushort* __restrict__ Vt, float* __restrict__ out)
{
    const int bid = blockIdx.x;
    const int super = bid >> 4, l = bid & 15;
    const int head_lin = super * 8 + (l & 7);     // 0..383
    const int qhalf = l >> 3;                     // 0..1
    const int b = head_lin / NHc, h = head_lin % NHc;

    const int wave = threadIdx.x >> 6;
    const int lane = threadIdx.x & 63;
    const int quad = lane >> 4, l16 = lane & 15;
    const int q0 = qhalf * 256 + wave * 64;       // wave owns q0..q0+63
    const int sw = l16 & 7;                       // XOR swizzle key

    const size_t head = (size_t)head_lin * (Sc_ * DHc);
    const ushort* __restrict__ Q = Qb + head;
    const ushort* __restrict__ K = Kt + head;
    const ushort* __restrict__ V = Vt + head;

    __shared__ __align__(16) ushort Plds[4][1024];   // wave-private, reused per utile

    short8v aq[4][2];
    #pragma unroll
    for (int u = 0; u < 4; ++u)
        #pragma unroll
        for (int hf = 0; hf < 2; ++hf)
            aq[u][hf] = *(const short8v*)
                &Q[(size_t)(q0 + u * 16 + l16) * DHc + hf * 32 + quad * 8];

    short8v ones;
    #pragma unroll
    for (int i = 0; i < 8; ++i) ones[i] = (short)0x3F80;   // bf16 1.0

    f32x4 o[4][4], rsum[4];
    #pragma unroll
    for (int u = 0; u < 4; ++u) {
        rsum[u] = (f32x4)(0.f);
        #pragma unroll
        for (int t = 0; t < 4; ++t) o[u][t] = (f32x4)(0.f);
    }

    for (int kb = 0; kb < 8; ++kb) {
        const ushort* Kb_ = K + kb * 4096;
        const ushort* Vb_ = V + kb * 4096;

        // K/V fragments, shared by all 4 u-tiles of this wave
        short8v kf[4][2], vf[4][2];
        #pragma unroll
        for (int t = 0; t < 4; ++t) {
            kf[t][0] = *(const short8v*)&Kb_[quad * 512 + (t * 16 + l16) * 8];
            kf[t][1] = *(const short8v*)&Kb_[(4 + quad) * 512 + (t * 16 + l16) * 8];
            vf[t][0] = *(const short8v*)&Vb_[quad * 512 + (t * 16 + l16) * 8];
            vf[t][1] = *(const short8v*)&Vb_[(4 + quad) * 512 + (t * 16 + l16) * 8];
        }

        #pragma unroll
        for (int u = 0; u < 4; ++u) {
            // S^T: D[key=quad*4+r][q=l16]
            f32x4 sa[4];
            #pragma unroll
            for (int t = 0; t < 4; ++t) {
                f32x4 s = __builtin_amdgcn_mfma_f32_16x16x32_bf16(
                    kf[t][0], aq[u][0], (f32x4)(0.f), 0, 0, 0);
                sa[t] = __builtin_amdgcn_mfma_f32_16x16x32_bf16(
                    kf[t][1], aq[u][1], s, 0, 0, 0);
            }

            // p = exp2(s~), pack to bf16, stage to LDS (wave-private)
            #pragma unroll
            for (int t = 0; t < 4; ++t) {
                float p0 = __builtin_amdgcn_exp2f(sa[t][0]);
                float p1 = __builtin_amdgcn_exp2f(sa[t][1]);
                float p2 = __builtin_amdgcn_exp2f(sa[t][2]);
                float p3 = __builtin_amdgcn_exp2f(sa[t][3]);
                ushort2 lo = f2b2(p0, p1);
                ushort2 hi = f2b2(p2, p3);
                ushort4 pk;
                pk.x = lo.x; pk.y = lo.y; pk.z = hi.x; pk.w = hi.y;
                int c = t * 2 + (quad >> 1);            // key chunk 0..7
                int addr = l16 * 64 + ((c ^ sw) * 8) + (quad & 1) * 4;
                *(ushort4*)&Plds[wave][addr] = pk;
            }

            // P A-frags (q = l16, key chunk = hf*4+quad, swizzled)
            short8v pa0 = *(const short8v*)&Plds[wave][l16 * 64 + ((quad ^ sw) * 8)];
            short8v pa1 = *(const short8v*)&Plds[wave][l16 * 64 + (((4 + quad) ^ sw) * 8)];

            // row sums via ones-MFMA
            rsum[u] = __builtin_amdgcn_mfma_f32_16x16x32_bf16(
                pa0, ones, rsum[u], 0, 0, 0);
            rsum[u] = __builtin_amdgcn_mfma_f32_16x16x32_bf16(
                pa1, ones, rsum[u], 0, 0, 0);

            // PV: O[q=quad*4+r][d=l16]
            #pragma unroll
            for (int t2 = 0; t2 < 4; ++t2) {
                o[u][t2] = __builtin_amdgcn_mfma_f32_16x16x32_bf16(
                    pa0, vf[t2][0], o[u][t2], 0, 0, 0);
                o[u][t2] = __builtin_amdgcn_mfma_f32_16x16x32_bf16(
                    pa1, vf[t2][1], o[u][t2], 0, 0, 0);
            }
        }
    }

    // Epilogue: normalize, tanh, store.
    #pragma unroll
    for (int u = 0; u < 4; ++u) {
        #pragma unroll
        for (int r = 0; r < 4; ++r) {
            float inv = __builtin_amdgcn_rcpf(rsum[u][r]);
            int q = q0 + u * 16 + quad * 4 + r;
            size_t base = ((size_t)b * Sc_ + q) * Hc + h * DHc;
            #pragma unroll
            for (int t2 = 0; t2 < 4; ++t2)
                out[base + t2 * 16 + l16] = fast_tanh(o[u][t2][r] * inv);
        }
    }
}

extern "C" void kernel_launch(void* const* d_in, const int* in_sizes, int n_in,
                              void* d_out, int out_size, void* d_ws, size_t ws_size,
                              hipStream_t stream) {
    const float* X  = (const float*)d_in[0];
    const float* Wq = (const float*)d_in[1];
    const float* bq = (const float*)d_in[2];
    const float* Wk = (const float*)d_in[3];
    const float* bk = (const float*)d_in[4];
    const float* Wv = (const float*)d_in[5];
    const float* bv = (const float*)d_in[6];
    float* out = (float*)d_out;

    ushort* Qb  = (ushort*)d_ws;
    ushort* Kt  = Qb + (size_t)Mc * Hc;
    ushort* Vt  = Kt + (size_t)Mc * Hc;
    ushort* Xt  = Vt + (size_t)Mc * Hc;
    ushort* Wt  = Xt + (size_t)Mc * Hc;
    float*  bbp = (float*)(Wt + (size_t)Ntot * Hc);

    convert_pack<<<dim3(1752), 256, 0, stream>>>(
        X, Wq, Wk, Wv, bq, bk, bv, Xt, Wt, bbp);

    qkv_mfma<<<dim3(576), 512, 0, stream>>>(Xt, Wt, bbp, Qb, Kt, Vt);

    attn_mfma<<<dim3(768), 256, 0, stream>>>(Qb, Kt, Vt, out);
}